// Round 2
// baseline (8707.114 us; speedup 1.0000x reference)
//
#include <hip/hip_runtime.h>
#include <cstdint>

// Problem constants (fixed by setup_inputs): B=8, n=m=2048, iters=20.
#define BB 8
#define NN 2048
#define MM 2048
#define ITERS 20
#define NBLK 1024   // 4 blocks/CU guaranteed by __launch_bounds__(256,4)
#define NTHR 256

// Workspace layout (bytes):
//   p2w     float4[B*M]  (xyz2 + price in .w)   offset 0        262144
//   packed  u64[B*M]                            offset 262144   131072
//   inv     int[B*M]                            offset 393216    65536
//   assign  int[B*N]                            offset 458752    65536
//   barrier ints (padded)                       offset 524288     4096
// total 528384 bytes; memset-to-0 once per launch (capture-legal).

// Two-level grid barrier: 32 groups x 32 blocks, monotonic counters.
// Episode separation proof: release of episode e requires all 1024 arrivals
// of episode e, so no block can post an episode e+1 arrival before every
// episode-e arrival landed -> (count & 31)==31 identifies the group leader.
__device__ __forceinline__ void gbar(int* grp, int* root, int* rel,
                                     int gid, int ep) {
  __threadfence();          // release our writes (and compiler barrier)
  __syncthreads();
  if (threadIdx.x == 0) {
    int v = atomicAdd(&grp[gid * 16], 1);         // 64B-padded counters
    if ((v & 31) == 31) {                         // last block of group
      int r = atomicAdd(root, 1);
      if ((r & 31) == 31)                         // last group overall
        __hip_atomic_store(rel, (r >> 5) + 1, __ATOMIC_RELEASE,
                           __HIP_MEMORY_SCOPE_AGENT);
    }
    while (__hip_atomic_load(rel, __ATOMIC_ACQUIRE,
                             __HIP_MEMORY_SCOPE_AGENT) < ep)
      __builtin_amdgcn_s_sleep(4);
  }
  __syncthreads();
  __threadfence();          // acquire side: L1 invalidate + compiler barrier
}

__global__ __launch_bounds__(NTHR, 4) void emd_kernel(
    const float* __restrict__ xyz1, const float* __restrict__ xyz2,
    const float* __restrict__ epsp, float* __restrict__ out,
    float4* p2w, unsigned long long* packed, int* inv, int* assign,
    int* bar_grp, int* bar_root, int* bar_rel) {
#pragma clang fp contract(off)
  const int b = blockIdx.x & 7;          // batch affinity: 128 blocks/batch
  const int sub = blockIdx.x >> 3;       // 0..127
  const int gid = blockIdx.x >> 5;       // barrier group 0..31
  const int tid = threadIdx.x;
  const int wave = tid >> 6, lane = tid & 63;
  int ep = 0;

  // ---- init: 16 entries per block (packed[] already zero via memset) ----
  if (tid < 16) {
    int gi = blockIdx.x * 16 + tid;      // covers [0, B*M)
    float x = xyz2[gi * 3 + 0];
    float y = xyz2[gi * 3 + 1];
    float z = xyz2[gi * 3 + 2];
    p2w[gi] = make_float4(x, y, z, 0.f); // price = 0 in .w
    inv[gi] = -1;
    assign[gi] = -1;
  }
  gbar(bar_grp, bar_root, bar_rel, gid, ++ep);

  const float eps = *epsp;
  const float NEG_INF = __int_as_float(0xff800000);
  const float4* pb = p2w + b * MM;

  for (int it = 0; it < ITERS; ++it) {
    // ---- bid phase: each wave owns 4 points of batch b ----
    for (int p = 0; p < 4; ++p) {
      int i = sub * 16 + wave * 4 + p;
      if (assign[b * NN + i] >= 0) continue;   // wave-uniform skip

      const float* x1p = xyz1 + (size_t)(b * NN + i) * 3;
      float x1 = x1p[0], y1 = x1p[1], z1 = x1p[2];
      float v1 = NEG_INF, v2 = NEG_INF;
      int j1 = 0;

      for (int t = 0; t < MM / 64; ++t) {
        int j = (t << 6) + lane;
        float4 q = pb[j];                 // xyz2 + price, one 16B load
        float dx = x1 - q.x;
        float dy = y1 - q.y;
        float dz = z1 - q.z;
        float c = dx * dx;
        c = c + dy * dy;                  // contract(off): matches numpy
        c = c + dz * dz;
        float v = -c - q.w;               // -cost - price, reference order
        bool c1 = v > v1;
        bool c2 = v > v2;
        v2 = c1 ? v1 : (c2 ? v : v2);
        v1 = c1 ? v : v1;
        j1 = c1 ? j : j1;
      }
      // butterfly top-2 merge, tie-break min j on equal v1
      for (int o = 1; o < 64; o <<= 1) {
        float ov1 = __shfl_xor(v1, o, 64);
        float ov2 = __shfl_xor(v2, o, 64);
        int oj1 = __shfl_xor(j1, o, 64);
        bool ow = (ov1 > v1) || (ov1 == v1 && oj1 < j1);
        float loser = ow ? v1 : ov1;
        v1 = ow ? ov1 : v1;
        j1 = ow ? oj1 : j1;
        v2 = fmaxf(fmaxf(v2, ov2), loser);
      }
      if (lane == 0) {
        float incr = (v1 - v2) + eps;     // top1 - top2 + eps
        unsigned int ib = __float_as_uint(incr);  // incr > 0 -> order-iso
        unsigned long long key =
            ((unsigned long long)ib << 32) | (unsigned int)(~(unsigned int)i);
        atomicMax(&packed[b * MM + j1], key);
      }
    }
    gbar(bar_grp, bar_root, bar_rel, gid, ++ep);

    // ---- update phase: 16 objects per block ----
    if (tid < 16) {
      int j = sub * 16 + tid;
      int idx = b * MM + j;
      unsigned long long key = packed[idx];
      if (key != 0ULL) {
        packed[idx] = 0ULL;
        float incr = __uint_as_float((unsigned int)(key >> 32));
        int w = (int)(~(unsigned int)(key & 0xffffffffULL));
        int prev = inv[idx];
        if (prev >= 0) assign[b * NN + prev] = -1;  // evict (disjoint writes)
        assign[b * NN + w] = j;
        inv[idx] = w;
        p2w[idx].w += incr;               // price += max bid increment
      }
    }
    gbar(bar_grp, bar_root, bar_rel, gid, ++ep);
  }

  // ---- final: dist + assignment (last gbar ordered the updates) ----
  if (tid < 16) {
    int idx = b * NN + sub * 16 + tid;    // covers [0, B*N)
    int a = assign[idx];
    float d = 0.f;
    if (a >= 0) {
      float4 q = pb[a];
      float dx = xyz1[idx * 3 + 0] - q.x;
      float dy = xyz1[idx * 3 + 1] - q.y;
      float dz = xyz1[idx * 3 + 2] - q.z;
      d = dx * dx;
      d = d + dy * dy;
      d = d + dz * dz;
    }
    out[idx] = d;
    out[BB * NN + idx] = (float)a;
  }
}

extern "C" void kernel_launch(void* const* d_in, const int* in_sizes, int n_in,
                              void* d_out, int out_size, void* d_ws, size_t ws_size,
                              hipStream_t stream) {
  const float* xyz1 = (const float*)d_in[0];
  const float* xyz2 = (const float*)d_in[1];
  const float* eps  = (const float*)d_in[2];
  // d_in[3] = iters (fixed at 20 by setup_inputs); hard-coded for capture.
  float* out = (float*)d_out;

  char* ws = (char*)d_ws;
  float4* p2w = (float4*)ws;
  unsigned long long* packed = (unsigned long long*)(ws + 262144);
  int* inv = (int*)(ws + 393216);
  int* assign = (int*)(ws + 458752);
  int* bar_grp = (int*)(ws + 524288);          // 32 counters, 64B apart
  int* bar_root = (int*)(ws + 524288 + 2048);
  int* bar_rel = (int*)(ws + 524288 + 2048 + 64);

  // zero packed + barrier state (ws is re-poisoned to 0xAA before every call)
  hipMemsetAsync(ws, 0, 528384, stream);

  void* args[] = {(void*)&xyz1, (void*)&xyz2, (void*)&eps, (void*)&out,
                  (void*)&p2w, (void*)&packed, (void*)&inv, (void*)&assign,
                  (void*)&bar_grp, (void*)&bar_root, (void*)&bar_rel};
  hipLaunchCooperativeKernel((const void*)emd_kernel, dim3(NBLK), dim3(NTHR),
                             args, 0, stream);
}

// Round 3
// 455.172 us; speedup vs baseline: 19.1293x; 19.1293x over previous
//
#include <hip/hip_runtime.h>
#include <cstdint>

// Problem constants (fixed by setup_inputs): B=8, n=m=2048, iters=20.
#define BB 8
#define NN 2048
#define MM 2048
#define ITERS 20

// Workspace layout (bytes):
//   p2f4   float4[B*M]   (xyz2 packed)        off 0       262144
//   pbuf   u64[2][B*M]   (bid keys, tagged)   off 262144  262144
//   price  float[2][B*M] (double-buffered)    off 524288  131072
//   inv    int[2][B*M]   (double-buffered)    off 655360  131072
// total 786432 bytes. No memsets needed: pack_kernel zeroes both pbuf
// halves; price[0]/inv[0] are never read (it==0 skips phase U).
//
// Bid key: (tag << 43) | (float_bits(incr) << 11) | (2047 - i)
//   tag = iteration+1 (1..20; 0 = empty). incr > 0 so float bit order is
//   value order; (2047-i) gives min-index tie-break; higher tags always
//   dominate via atomicMax, so stale keys never need clearing.

__global__ __launch_bounds__(256) void pack_kernel(
    const float* __restrict__ xyz2, float4* __restrict__ p2f4,
    unsigned long long* __restrict__ pbuf) {
  int idx = blockIdx.x * 256 + threadIdx.x;  // [0, B*M)
  p2f4[idx] = make_float4(xyz2[idx * 3], xyz2[idx * 3 + 1],
                          xyz2[idx * 3 + 2], 0.f);
  pbuf[idx] = 0ULL;
  pbuf[BB * MM + idx] = 0ULL;
}

// One kernel per auction iteration. Each block:
//  U) redundantly recomputes the whole batch's post-update price/inv as a
//     PURE function of (pb_read tags, pr_old, iv_old) — identical in every
//     block, so no races; prices go to LDS, and the block flags which of
//     its own 16 points are assigned (inv inversion on the fly).
//     sub==0 block also writes price/inv to the NEW global buffers for the
//     next kernel. All reads hit OLD buffers (frozen this kernel).
//  B) bids for its unassigned points: 1 wave per point, top-2 over 2048
//     objects, butterfly merge, one u64 atomicMax into pb_write.
__global__ __launch_bounds__(256) void iter_kernel(
    const float* __restrict__ xyz1, const float4* __restrict__ p2f4,
    const float* __restrict__ epsp,
    const unsigned long long* __restrict__ pb_read,
    unsigned long long* __restrict__ pb_write,
    const float* __restrict__ pr_old, float* __restrict__ pr_new,
    const int* __restrict__ iv_old, int* __restrict__ iv_new,
    int it) {
#pragma clang fp contract(off)
  __shared__ float lds_price[MM];
  __shared__ int lds_assigned[16];
  const int b = blockIdx.x >> 7;           // 128 consecutive blocks per batch
  const int sub = blockIdx.x & 127;        // 0..127
  const int base = sub * 16;               // first point owned by this block
  const int tid = threadIdx.x;
  const int wave = tid >> 6, lane = tid & 63;

  if (tid < 16) lds_assigned[tid] = 0;
  __syncthreads();

  // ---- phase U: apply previous kernel's bids (tag == it) ----
  if (it > 0) {
    for (int s = 0; s < 8; ++s) {
      int j = s * 256 + tid;
      int idx = b * MM + j;
      unsigned long long key = pb_read[idx];
      float pr = pr_old[idx];
      int iv = iv_old[idx];
      if ((int)(key >> 43) == it) {        // fresh bid for object j
        pr = pr + __uint_as_float((unsigned int)(key >> 11));
        iv = 2047 - (int)(key & 0x7FF);
      }
      lds_price[j] = pr;
      if (iv >= base && iv < base + 16)    // inv is injective: race-free
        lds_assigned[iv - base] = 1;
      if (sub == 0) { pr_new[idx] = pr; iv_new[idx] = iv; }
    }
  } else {
    for (int s = 0; s < 8; ++s) lds_price[s * 256 + tid] = 0.f;
    if (sub == 0) {
      for (int s = 0; s < 8; ++s) {
        int idx = b * MM + s * 256 + tid;
        pr_new[idx] = 0.f;
        iv_new[idx] = -1;
      }
    }
  }
  __syncthreads();

  // ---- phase B: bid for this block's unassigned points ----
  const float eps = *epsp;
  const float NEG_INF = __int_as_float(0xff800000);
  const float4* pb4 = p2f4 + b * MM;

  for (int p = 0; p < 4; ++p) {
    int li = wave * 4 + p;
    if (lds_assigned[li]) continue;        // wave-uniform skip
    int i = base + li;

    const float* x1p = xyz1 + (size_t)(b * NN + i) * 3;
    float x1 = x1p[0], y1 = x1p[1], z1 = x1p[2];
    float v1 = NEG_INF, v2 = NEG_INF;
    int j1 = 0;

    for (int t = 0; t < MM / 64; ++t) {
      int j = (t << 6) + lane;
      float4 q = pb4[j];
      float pj = lds_price[j];
      float dx = x1 - q.x;
      float dy = y1 - q.y;
      float dz = z1 - q.z;
      float c = dx * dx;
      c = c + dy * dy;                     // contract(off): matches numpy
      c = c + dz * dz;
      float v = -c - pj;                   // -cost - price, reference order
      bool c1 = v > v1;
      bool c2 = v > v2;
      v2 = c1 ? v1 : (c2 ? v : v2);
      v1 = c1 ? v : v1;
      j1 = c1 ? j : j1;
    }
    // butterfly top-2 merge, tie-break min j on equal v1
    for (int o = 1; o < 64; o <<= 1) {
      float ov1 = __shfl_xor(v1, o, 64);
      float ov2 = __shfl_xor(v2, o, 64);
      int oj1 = __shfl_xor(j1, o, 64);
      bool ow = (ov1 > v1) || (ov1 == v1 && oj1 < j1);
      float loser = ow ? v1 : ov1;
      v1 = ow ? ov1 : v1;
      j1 = ow ? oj1 : j1;
      v2 = fmaxf(fmaxf(v2, ov2), loser);
    }
    if (lane == 0) {
      float incr = (v1 - v2) + eps;        // top1 - top2 + eps
      unsigned long long key =
          ((unsigned long long)(unsigned)(it + 1) << 43) |
          ((unsigned long long)__float_as_uint(incr) << 11) |
          (unsigned long long)(2047 - i);
      atomicMax(&pb_write[b * MM + j1], key);
    }
  }
}

// Final: apply tag==ITERS bids on the fly, invert inv into LDS, emit
// dist + assignment for this block's 16 points.
__global__ __launch_bounds__(256) void final_kernel(
    const float* __restrict__ xyz1, const float4* __restrict__ p2f4,
    const unsigned long long* __restrict__ pb_read,
    const int* __restrict__ iv_old, float* __restrict__ out) {
#pragma clang fp contract(off)
  __shared__ int lds_owner[16];
  const int b = blockIdx.x >> 7;
  const int sub = blockIdx.x & 127;
  const int base = sub * 16;
  const int tid = threadIdx.x;

  if (tid < 16) lds_owner[tid] = -1;
  __syncthreads();

  for (int s = 0; s < 8; ++s) {
    int j = s * 256 + tid;
    int idx = b * MM + j;
    unsigned long long key = pb_read[idx];
    int iv = ((int)(key >> 43) == ITERS) ? (2047 - (int)(key & 0x7FF))
                                         : iv_old[idx];
    if (iv >= base && iv < base + 16) lds_owner[iv - base] = j;
  }
  __syncthreads();

  if (tid < 16) {
    int i = base + tid;
    int idx = b * NN + i;
    int a = lds_owner[tid];
    float d = 0.f;
    if (a >= 0) {
      float4 q = p2f4[b * MM + a];
      float dx = xyz1[idx * 3 + 0] - q.x;
      float dy = xyz1[idx * 3 + 1] - q.y;
      float dz = xyz1[idx * 3 + 2] - q.z;
      d = dx * dx;
      d = d + dy * dy;
      d = d + dz * dz;
    }
    out[idx] = d;
    out[BB * NN + idx] = (float)a;         // assignment as float32 values
  }
}

extern "C" void kernel_launch(void* const* d_in, const int* in_sizes, int n_in,
                              void* d_out, int out_size, void* d_ws, size_t ws_size,
                              hipStream_t stream) {
  const float* xyz1 = (const float*)d_in[0];
  const float* xyz2 = (const float*)d_in[1];
  const float* eps  = (const float*)d_in[2];
  // d_in[3] = iters (fixed at 20 by setup_inputs); hard-coded for capture.
  float* out = (float*)d_out;

  char* ws = (char*)d_ws;
  float4* p2f4 = (float4*)ws;
  unsigned long long* pbuf = (unsigned long long*)(ws + 262144); // [2][B*M]
  float* price = (float*)(ws + 524288);                          // [2][B*M]
  int* inv = (int*)(ws + 655360);                                // [2][B*M]

  pack_kernel<<<BB * MM / 256, 256, 0, stream>>>(xyz2, p2f4, pbuf);

  for (int it = 0; it < ITERS; ++it) {
    // kernel it reads OLD = index (it&1), writes NEW = index ((it+1)&1);
    // bids: write pbuf[it&1], consume pbuf[(it-1)&1] == pbuf[(it+1)&1].
    const unsigned long long* pb_read = pbuf + (size_t)((it + 1) & 1) * BB * MM;
    unsigned long long* pb_write = pbuf + (size_t)(it & 1) * BB * MM;
    const float* pr_old = price + (size_t)(it & 1) * BB * MM;
    float* pr_new = price + (size_t)((it + 1) & 1) * BB * MM;
    const int* iv_old = inv + (size_t)(it & 1) * BB * MM;
    int* iv_new = inv + (size_t)((it + 1) & 1) * BB * MM;
    iter_kernel<<<1024, 256, 0, stream>>>(xyz1, p2f4, eps, pb_read, pb_write,
                                          pr_old, pr_new, iv_old, iv_new, it);
  }

  final_kernel<<<1024, 256, 0, stream>>>(
      xyz1, p2f4, pbuf + (size_t)((ITERS - 1) & 1) * BB * MM,
      inv + (size_t)(ITERS & 1) * BB * MM, out);
}

// Round 4
// 319.871 us; speedup vs baseline: 27.2207x; 1.4230x over previous
//
#include <hip/hip_runtime.h>
#include <cstdint>

// Problem constants (fixed by setup_inputs): B=8, n=m=2048, iters=20.
#define BB 8
#define NN 2048
#define MM 2048
#define ITERS 20

typedef unsigned long long u64;

// Workspace layout (bytes):
//   p2w    float4[2][B*M]  xyz2 + folded price in .w   off 0       524288
//   pbuf   u64[2][B*M]     tagged bid keys             off 524288  262144
//   assign int[2][B*N]     forward map, dbuffered      off 786432  131072
//   bidt   int[B*N]        last bid target per point   off 917504   65536
// total 983040 bytes.
//
// Bid key: (tag << 43) | (float_bits(incr) << 11) | (2047 - i)
//   tag = it+1 (1..20; 0 = empty). incr > 0 so float bit order == value
//   order; (2047-i) gives min-index tie-break; higher tags strictly
//   dominate via atomicMax, so stale keys never need clearing.
//
// Buffer rotation: kernel K reads p2w[K&1], pbuf[(K+1)&1], assign[K&1];
// writes p2w[(K+1)&1] (writer blocks), pbuf[K&1] (bids), assign[(K+1)&1].

__global__ __launch_bounds__(256) void pack_kernel(
    const float* __restrict__ xyz2, float4* __restrict__ p2w,
    u64* __restrict__ pbuf) {
  int idx = blockIdx.x * 256 + threadIdx.x;  // [0, B*M)
  p2w[idx] = make_float4(xyz2[idx * 3], xyz2[idx * 3 + 1],
                         xyz2[idx * 3 + 2], 0.f);
  pbuf[idx] = 0ULL;
  pbuf[BB * MM + idx] = 0ULL;
}

// One kernel per auction iteration; one wave per point.
//  1) writer duty (first 8 sub-blocks/batch): fold tag-K keys into price,
//     write p2w_new for the next kernel. Unique j per lane: race-free.
//  2) status: O(1) per point. Assigned point i owning j is evicted iff
//     keys[j] has tag K (any fresh bid replaces the owner — i itself never
//     bids while assigned). Unassigned bidder i won iff keys[bidt[i]]
//     decodes winner == i (its own tag-K key guarantees tag matches).
//  3) unassigned waves scan all 2048 objects with the tag-K price fold
//     applied inline: pr = price_old + incr — the exact reference add.
__global__ __launch_bounds__(256) void iter_kernel(
    const float* __restrict__ xyz1,
    const float4* __restrict__ p2w_old, float4* __restrict__ p2w_new,
    const float* __restrict__ epsp,
    const u64* __restrict__ pb_read, u64* __restrict__ pb_write,
    const int* __restrict__ assign_old, int* __restrict__ assign_new,
    int* __restrict__ bidt, int it) {
#pragma clang fp contract(off)
  const int blk = blockIdx.x;
  const int b = blk & 7;                 // batch = XCD affinity (perf only)
  const int sub = blk >> 3;              // 0..511
  const int tid = threadIdx.x;
  const int wave = tid >> 6, lane = tid & 63;
  const int i = (sub << 2) + wave;       // point in [0, 2048)
  const int gi = b * NN + i;
  const u64* keys = pb_read + b * MM;

  // ---- 1) writer duty: materialize folded prices for next kernel ----
  if (sub < 8) {
    int j = sub * 256 + tid;
    int idx = b * MM + j;
    float4 q = p2w_old[idx];
    if (it > 0) {
      u64 k = pb_read[idx];
      if ((int)(k >> 43) == it)
        q.w = q.w + __uint_as_float((unsigned)(k >> 11));  // reference add
    }
    p2w_new[idx] = q;
  }

  // ---- 2) status (wave-uniform) ----
  bool need_bid;
  int cur = -1;
  if (it == 0) {
    need_bid = true;                      // everyone starts unassigned
  } else {
    int a_old = assign_old[gi];
    if (a_old >= 0) {
      u64 k = keys[a_old];
      if ((int)(k >> 43) == it) {
        need_bid = true;                  // evicted by a fresh bid
      } else {
        need_bid = false; cur = a_old;    // keeps its object
      }
    } else {
      int jt = bidt[gi];                  // we bid last kernel: tag==it there
      u64 k = keys[jt];
      int w = 2047 - (int)(k & 0x7FF);
      if (w == i) { need_bid = false; cur = jt; }  // won
      else need_bid = true;                        // outbid
    }
  }
  if (lane == 0) assign_new[gi] = need_bid ? -1 : cur;
  if (!need_bid) return;                  // wave-uniform exit

  // ---- 3) bid: top-2 scan with inline price fold ----
  const float eps = *epsp;
  const float* x1p = xyz1 + (size_t)gi * 3;
  float x1 = x1p[0], y1 = x1p[1], z1 = x1p[2];
  const float4* pold = p2w_old + b * MM;
  const float NEG_INF = __int_as_float(0xff800000);
  float v1 = NEG_INF, v2 = NEG_INF;
  int j1 = 0;

  for (int t = 0; t < MM / 64; ++t) {
    int j = (t << 6) + lane;
    float4 q = pold[j];
    float pr = q.w;
    if (it > 0) {
      u64 k = keys[j];
      if ((int)(k >> 43) == it)
        pr = pr + __uint_as_float((unsigned)(k >> 11));   // reference add
    }
    float dx = x1 - q.x;
    float dy = y1 - q.y;
    float dz = z1 - q.z;
    float c = dx * dx;
    c = c + dy * dy;                      // contract(off): matches numpy
    c = c + dz * dz;
    float v = -c - pr;                    // -cost - price, reference order
    bool c1 = v > v1;
    bool c2 = v > v2;
    v2 = c1 ? v1 : (c2 ? v : v2);
    v1 = c1 ? v : v1;
    j1 = c1 ? j : j1;
  }
  // butterfly top-2 merge, tie-break min j on equal v1
  for (int o = 1; o < 64; o <<= 1) {
    float ov1 = __shfl_xor(v1, o, 64);
    float ov2 = __shfl_xor(v2, o, 64);
    int oj1 = __shfl_xor(j1, o, 64);
    bool ow = (ov1 > v1) || (ov1 == v1 && oj1 < j1);
    float loser = ow ? v1 : ov1;
    v1 = ow ? ov1 : v1;
    j1 = ow ? oj1 : j1;
    v2 = fmaxf(fmaxf(v2, ov2), loser);
  }
  if (lane == 0) {
    float incr = (v1 - v2) + eps;         // top1 - top2 + eps
    u64 key = ((u64)(unsigned)(it + 1) << 43) |
              ((u64)__float_as_uint(incr) << 11) |
              (u64)(unsigned)(2047 - i);
    atomicMax(&pb_write[b * MM + j1], key);
    bidt[gi] = j1;
  }
}

// Final: resolve tag-ITERS bids per point (same O(1) status logic), emit
// dist + assignment.
__global__ __launch_bounds__(256) void final_kernel(
    const float* __restrict__ xyz1, const float4* __restrict__ p2f4,
    const u64* __restrict__ pb_last, const int* __restrict__ assign_old,
    const int* __restrict__ bidt, float* __restrict__ out) {
#pragma clang fp contract(off)
  int idx = blockIdx.x * 256 + threadIdx.x;  // [0, B*N)
  int b = idx >> 11, i = idx & (NN - 1);
  const u64* keys = pb_last + b * MM;

  int a_old = assign_old[idx];
  int cur;
  if (a_old >= 0) {
    u64 k = keys[a_old];
    cur = ((int)(k >> 43) == ITERS) ? -1 : a_old;   // evicted at the end?
  } else {
    int jt = bidt[idx];
    u64 k = keys[jt];
    cur = ((2047 - (int)(k & 0x7FF)) == i) ? jt : -1;
  }

  float d = 0.f;
  if (cur >= 0) {
    float4 q = p2f4[b * MM + cur];
    float dx = xyz1[idx * 3 + 0] - q.x;
    float dy = xyz1[idx * 3 + 1] - q.y;
    float dz = xyz1[idx * 3 + 2] - q.z;
    d = dx * dx;
    d = d + dy * dy;
    d = d + dz * dz;
  }
  out[idx] = d;
  out[BB * NN + idx] = (float)cur;        // assignment as float32 values
}

extern "C" void kernel_launch(void* const* d_in, const int* in_sizes, int n_in,
                              void* d_out, int out_size, void* d_ws, size_t ws_size,
                              hipStream_t stream) {
  const float* xyz1 = (const float*)d_in[0];
  const float* xyz2 = (const float*)d_in[1];
  const float* eps  = (const float*)d_in[2];
  // d_in[3] = iters (fixed at 20 by setup_inputs); hard-coded for capture.
  float* out = (float*)d_out;

  char* ws = (char*)d_ws;
  float4* p2w = (float4*)ws;                       // [2][B*M]
  u64* pbuf = (u64*)(ws + 524288);                 // [2][B*M]
  int* assign = (int*)(ws + 786432);               // [2][B*N]
  int* bidt = (int*)(ws + 917504);                 // [B*N]

  pack_kernel<<<BB * MM / 256, 256, 0, stream>>>(xyz2, p2w, pbuf);

  for (int it = 0; it < ITERS; ++it) {
    const float4* po = p2w + (size_t)(it & 1) * BB * MM;
    float4* pn = p2w + (size_t)((it + 1) & 1) * BB * MM;
    const u64* pr = pbuf + (size_t)((it + 1) & 1) * BB * MM;
    u64* pw = pbuf + (size_t)(it & 1) * BB * MM;
    const int* ao = assign + (size_t)(it & 1) * BB * NN;
    int* an = assign + (size_t)((it + 1) & 1) * BB * NN;
    iter_kernel<<<4096, 256, 0, stream>>>(xyz1, po, pn, eps, pr, pw, ao, an,
                                          bidt, it);
  }

  // kernel 19 wrote pbuf[1] (tag 20) and assign[0]
  final_kernel<<<BB * NN / 256, 256, 0, stream>>>(
      xyz1, p2w, pbuf + (size_t)(BB * MM), assign, bidt, out);
}